// Round 4
// baseline (399.396 us; speedup 1.0000x reference)
//
#include <hip/hip_runtime.h>

// MultiHeadAttention B=4,S=2048,D=1024,H=16,depth=64.
// R4: mask folded into QK^T accumulator init (no Cm LDS, no mask adds, no
// zero-init movs), attn LDS 32KB -> 4+ blocks/CU, merged cvt dispatch,
// GEMM launch_bounds 4.

typedef unsigned short ushort_t;
typedef __bf16          b16x8 __attribute__((ext_vector_type(8)));
typedef unsigned short  u16x8 __attribute__((ext_vector_type(8)));
typedef unsigned short  u16x4 __attribute__((ext_vector_type(4)));
typedef unsigned int    u32x4 __attribute__((ext_vector_type(4)));
typedef float           f32x4 __attribute__((ext_vector_type(4)));
typedef int             i32x4 __attribute__((ext_vector_type(4)));

#define B_ 4
#define S_ 2048
#define D_ 1024
#define H_ 16
#define DEPTH_ 64
#define LOG2E 1.4426950408889634f
#define MASKC (-1.4426950408889634e9f)

__device__ __forceinline__ unsigned short f2bf(float f) {
  unsigned u = __builtin_bit_cast(unsigned, f);
  u += 0x7FFFu + ((u >> 16) & 1u);   // RTNE
  return (unsigned short)(u >> 16);
}

__device__ __forceinline__ unsigned pack_trunc(float lo, float hi) {
#if __has_builtin(__builtin_amdgcn_perm)
  return __builtin_amdgcn_perm(__builtin_bit_cast(unsigned, hi),
                               __builtin_bit_cast(unsigned, lo), 0x07060302u);
#else
  return (__builtin_bit_cast(unsigned, hi) & 0xFFFF0000u) |
         (__builtin_bit_cast(unsigned, lo) >> 16);
#endif
}

#if __has_builtin(__builtin_amdgcn_exp2f)
#define EXP2F(x) __builtin_amdgcn_exp2f(x)
#else
#define EXP2F(x) exp2f(x)
#endif

#define GLD16(gp, lp) __builtin_amdgcn_global_load_lds( \
    (__attribute__((address_space(1))) void*)(gp),       \
    (__attribute__((address_space(3))) void*)(lp), 16, 0, 0)

#define MFMA_BF16(a, b, c) __builtin_amdgcn_mfma_f32_16x16x32_bf16( \
    __builtin_bit_cast(b16x8, (a)), __builtin_bit_cast(b16x8, (b)), (c), 0, 0, 0)

// ---------------- merged convert kernel ----------------
// y<3: activations fp32->bf16 (x in [0,8192))
// y==3: weight transpose-convert (x in [0,4096): weight x>>10, tile x&1023)

__global__ void cvt_kernel(const float* __restrict__ q, const float* __restrict__ k,
                           const float* __restrict__ v,
                           const float* __restrict__ Wq, const float* __restrict__ Wk,
                           const float* __restrict__ Wv, const float* __restrict__ Wo,
                           ushort_t* __restrict__ qb, ushort_t* __restrict__ kb,
                           ushort_t* __restrict__ vb,
                           ushort_t* __restrict__ Wqt, ushort_t* __restrict__ Wkt,
                           ushort_t* __restrict__ Wvt, ushort_t* __restrict__ Wot) {
  __shared__ float t[32][33];
  const int y = blockIdx.y;
  if (y < 3) {
    const float* src = y == 0 ? q : y == 1 ? k : v;
    ushort_t*    dst = y == 0 ? qb : y == 1 ? kb : vb;
    size_t i = ((size_t)blockIdx.x * 256 + threadIdx.x) * 4;
    float4 f = *(const float4*)(src + i);
    u16x4 o;
    o[0] = f2bf(f.x); o[1] = f2bf(f.y); o[2] = f2bf(f.z); o[3] = f2bf(f.w);
    *(u16x4*)(dst + i) = o;
    return;
  }
  const int x = blockIdx.x;
  if (x >= 4096) return;
  const int z = x >> 10, tile = x & 1023;
  const float* W = z == 0 ? Wq : z == 1 ? Wk : z == 2 ? Wv : Wo;
  ushort_t*   Wt = z == 0 ? Wqt : z == 1 ? Wkt : z == 2 ? Wvt : Wot;
  const int xx = threadIdx.x & 31, y0 = threadIdx.x >> 5;
  const int kt = (tile & 31) * 32, nt = (tile >> 5) * 32;
#pragma unroll
  for (int r = 0; r < 4; r++) {
    int row = y0 + r * 8;
    t[row][xx] = W[(size_t)(kt + row) * D_ + nt + xx];
  }
  __syncthreads();
#pragma unroll
  for (int r = 0; r < 4; r++) {
    int row = y0 + r * 8;
    Wt[(size_t)(nt + row) * D_ + kt + xx] = f2bf(t[xx][row]);
  }
}

// ---------------- GEMM core: 128x128 tile, BK=64, XOR-swizzled LDS ----------------

__device__ __forceinline__ void gemm_core(const ushort_t* __restrict__ A,
                                          const ushort_t* __restrict__ Bt,
                                          ushort_t* As, ushort_t* Bs,
                                          int tm, int tn, f32x4* acc) {
  const int tid = threadIdx.x;
  const int lane = tid & 63, wid = tid >> 6;
  const int wm = (wid >> 1) * 64, wn = (wid & 1) * 64;
  const int srow = lane >> 3;
  const int scol = ((lane & 7) ^ srow) * 8;
  const ushort_t* gA[4];
  const ushort_t* gB[4];
#pragma unroll
  for (int c = 0; c < 4; c++) {
    const int ch = wid * 4 + c;
    gA[c] = A  + (size_t)(tm + ch * 8 + srow) * D_ + scol;
    gB[c] = Bt + (size_t)(tn + ch * 8 + srow) * D_ + scol;
  }
  const int fr = lane & 15, fq = lane >> 4;
#pragma unroll
  for (int i = 0; i < 16; i++) acc[i] = f32x4{0.f, 0.f, 0.f, 0.f};
  for (int k0 = 0; k0 < D_; k0 += 64) {
    __syncthreads();
#pragma unroll
    for (int c = 0; c < 4; c++) {
      const int ch = wid * 4 + c;
      GLD16(gA[c] + k0, As + ch * 512);
      GLD16(gB[c] + k0, Bs + ch * 512);
    }
    __syncthreads();
#pragma unroll
    for (int kh = 0; kh < 2; kh++) {
      const int coff = (((kh * 4 + fq) ^ (fr & 7))) * 8;
      u16x8 af[4], bf[4];
#pragma unroll
      for (int mi = 0; mi < 4; mi++)
        af[mi] = *(const u16x8*)(As + (wm + mi * 16 + fr) * 64 + coff);
#pragma unroll
      for (int ni = 0; ni < 4; ni++)
        bf[ni] = *(const u16x8*)(Bs + (wn + ni * 16 + fr) * 64 + coff);
#pragma unroll
      for (int mi = 0; mi < 4; mi++)
#pragma unroll
        for (int ni = 0; ni < 4; ni++)
          acc[mi * 4 + ni] = MFMA_BF16(af[mi], bf[ni], acc[mi * 4 + ni]);
    }
  }
}

__device__ __forceinline__ int sigma32(int k5) {
  return ((k5 & 15) >> 2) * 8 + ((k5 >> 4) & 1) * 4 + (k5 & 3);
}

__device__ __forceinline__ void gemm_tile_swizzle(int bx, int& tm, int& tn) {
  const int xcd = bx & 7, j = bx >> 3;
  tn = (j & 7) * 128;
  tm = (((j >> 3) << 3) | xcd) * 128;
}

// z=0: Q*log2e/8 -> Qh [B,H,S,64]; z=1: K -> Kh; z=2: V -> Vht [B,H,64,S~sigma]
__global__ __launch_bounds__(256, 4) void qkv_gemm_kernel(
    const ushort_t* __restrict__ qb, const ushort_t* __restrict__ kb, const ushort_t* __restrict__ vb,
    const ushort_t* __restrict__ Wqt, const ushort_t* __restrict__ Wkt, const ushort_t* __restrict__ Wvt,
    const float* __restrict__ bq, const float* __restrict__ bk, const float* __restrict__ bv,
    ushort_t* __restrict__ Qh, ushort_t* __restrict__ Kh, ushort_t* __restrict__ Vht) {
  __shared__ __align__(16) ushort_t smem[128 * 136];
  ushort_t* As = smem;
  ushort_t* Bs = smem + 8192;
  const int z = blockIdx.z;
  const ushort_t* A  = z == 0 ? qb : z == 1 ? kb : vb;
  const ushort_t* Bt = z == 0 ? Wqt : z == 1 ? Wkt : Wvt;
  const float* bias  = z == 0 ? bq : z == 1 ? bk : bv;
  int tm, tn;
  gemm_tile_swizzle(blockIdx.x, tm, tn);
  f32x4 acc[16];
  gemm_core(A, Bt, As, Bs, tm, tn, acc);
  const int lane = threadIdx.x & 63, wid = threadIdx.x >> 6;
  const int wm = (wid >> 1) * 64, wn = (wid & 1) * 64;
  const int fr = lane & 15, rq = (lane >> 4) * 4;
  if (z == 2) {
    __syncthreads();
    ushort_t* trans = smem;
#pragma unroll
    for (int ni = 0; ni < 4; ni++) {
      const int n = wn + ni * 16 + fr;
      const float bb = bias[tn + n];
#pragma unroll
      for (int mi = 0; mi < 4; mi++) {
#pragma unroll
        for (int r = 0; r < 4; r++) {
          const int m = wm + mi * 16 + rq + r;
          const int mp = (m & ~31) + sigma32(m & 31);
          trans[n * 136 + mp] = f2bf(acc[mi * 4 + ni][r] + bb);
        }
      }
    }
    __syncthreads();
    const int n = threadIdx.x >> 1, hf = threadIdx.x & 1;
    const int col = tn + n, hh = col >> 6, dd = col & 63;
    const int bI = tm >> 11, sb = (tm & 2047) + hf * 64;
    ushort_t* dst = Vht + ((size_t)(bI * H_ + hh) * DEPTH_ + dd) * S_ + sb;
    const ushort_t* srcp = trans + n * 136 + hf * 64;
#pragma unroll
    for (int i = 0; i < 8; i++)
      *(u16x8*)(dst + i * 8) = *(const u16x8*)(srcp + i * 8);
  } else {
    ushort_t* outp = (z == 0) ? Qh : Kh;
    const float qscale = (z == 0) ? 0.125f * LOG2E : 1.0f;
#pragma unroll
    for (int ni = 0; ni < 4; ni++) {
      const int col = tn + wn + ni * 16 + fr;
      const float bb = bias[col];
      const int h = col >> 6, dd = col & 63;
#pragma unroll
      for (int mi = 0; mi < 4; mi++) {
#pragma unroll
        for (int r = 0; r < 4; r++) {
          const int m = tm + wm + mi * 16 + rq + r;
          const int b = m >> 11, s = m & 2047;
          outp[((size_t)(b * H_ + h) * S_ + s) * DEPTH_ + dd] =
              f2bf((acc[mi * 4 + ni][r] + bb) * qscale);
        }
      }
    }
  }
}

__global__ __launch_bounds__(256, 4) void out_gemm_kernel(
    const ushort_t* __restrict__ ctx, const ushort_t* __restrict__ Wot,
    const float* __restrict__ bo, float* __restrict__ out) {
  __shared__ __align__(16) ushort_t As[8192], Bs[8192];
  int tm, tn;
  gemm_tile_swizzle(blockIdx.x, tm, tn);
  f32x4 acc[16];
  gemm_core(ctx, Wot, As, Bs, tm, tn, acc);
  const int lane = threadIdx.x & 63, wid = threadIdx.x >> 6;
  const int wm = (wid >> 1) * 64, wn = (wid & 1) * 64;
  const int fr = lane & 15, rq = (lane >> 4) * 4;
#pragma unroll
  for (int ni = 0; ni < 4; ni++) {
    const int col = tn + wn + ni * 16 + fr;
    const float bb = bo[col];
#pragma unroll
    for (int mi = 0; mi < 4; mi++) {
#pragma unroll
      for (int r = 0; r < 4; r++) {
        const int m = tm + wm + mi * 16 + rq + r;
        out[(size_t)m * D_ + col] = acc[mi * 4 + ni][r] + bb;
      }
    }
  }
}

// ---------------- flash attention, S^T orientation, mask in acc-init ----------------

__global__ __launch_bounds__(256, 4) void attn_kernel(
    const ushort_t* __restrict__ Qh, const ushort_t* __restrict__ Kh,
    const ushort_t* __restrict__ Vht, const int* __restrict__ mask,
    ushort_t* __restrict__ ctx) {
  __shared__ __align__(16) ushort_t Ks[128 * 64];   // [key][d], chunks ^ (row&7)
  __shared__ __align__(16) ushort_t Vs[64 * 128];   // [d][key-sigma], chunks ^ (row&15)
  const int tid = threadIdx.x, lane = tid & 63, wid = tid >> 6;
  const int id = blockIdx.x;
  const int xcd = id & 7, j = id >> 3;
  const int qt = j & 15;
  const int bh = xcd * 8 + (j >> 4);
  const int b = bh >> 4, h = bh & 15;
  const size_t base = (size_t)bh * (S_ * DEPTH_);
  const int fr = lane & 15, fq = lane >> 4;

  const int* mrow = mask + b * S_;

  u16x8 qf[2][2];
#pragma unroll
  for (int nq = 0; nq < 2; nq++)
#pragma unroll
    for (int kc = 0; kc < 2; kc++)
      qf[nq][kc] = *(const u16x8*)(Qh + base +
          (size_t)(qt * 128 + wid * 32 + nq * 16 + fr) * DEPTH_ + kc * 32 + fq * 8);

  u16x8 ones_f;
  {
    const unsigned short o = (fr == 0) ? (unsigned short)0x3F80 : (unsigned short)0;
#pragma unroll
    for (int jj = 0; jj < 8; jj++) ones_f[jj] = o;
  }

  f32x4 Oa[4][2];
  f32x4 lacc[2];
#pragma unroll
  for (int di = 0; di < 4; di++)
#pragma unroll
    for (int nq = 0; nq < 2; nq++) Oa[di][nq] = f32x4{0.f, 0.f, 0.f, 0.f};
#pragma unroll
  for (int nq = 0; nq < 2; nq++) lacc[nq] = f32x4{0.f, 0.f, 0.f, 0.f};

  const int krow = lane >> 3;
  const int kcolL = ((lane & 7) ^ (krow & 7)) * 8;
  const int vrowc = lane >> 4;
  const int koff0 = ((0 + fq) ^ (fr & 7)) * 8;
  const int koff1 = ((4 + fq) ^ (fr & 7)) * 8;

  for (int kt = 0; kt < 16; kt++) {
    __syncthreads();
    // mask prefetch (latency hides behind staging + barrier)
    i32x4 mk[8];
#pragma unroll
    for (int t = 0; t < 8; t++)
      mk[t] = *(const i32x4*)(mrow + kt * 128 + t * 16 + fq * 4);
#pragma unroll
    for (int c = 0; c < 4; c++) {
      const int ch = wid * 4 + c;
      GLD16(Kh + base + (size_t)(kt * 128 + ch * 8 + krow) * DEPTH_ + kcolL, Ks + ch * 512);
      const int vrow = ch * 4 + vrowc;
      const int vcolL = ((lane & 15) ^ (vrow & 15)) * 8;
      GLD16(Vht + base + (size_t)vrow * S_ + kt * 128 + vcolL, Vs + ch * 512);
    }
    __syncthreads();
    // mask -> additive log2-domain C-init values
    f32x4 cmv[8];
#pragma unroll
    for (int t = 0; t < 8; t++)
#pragma unroll
      for (int r = 0; r < 4; r++)
        cmv[t][r] = mk[t][r] ? MASKC : 0.0f;

#pragma unroll
    for (int ks = 0; ks < 4; ks++) {
      const int nk0 = ks * 2, nk1 = nk0 + 1;
      const ushort_t* kr0 = Ks + (nk0 * 16 + fr) * 64;
      const ushort_t* kr1 = Ks + (nk1 * 16 + fr) * 64;
      const u16x8 a00 = *(const u16x8*)(kr0 + koff0);
      const u16x8 a01 = *(const u16x8*)(kr0 + koff1);
      const u16x8 a10 = *(const u16x8*)(kr1 + koff0);
      const u16x8 a11 = *(const u16x8*)(kr1 + koff1);
      f32x4 st0[2], st1[2];
#pragma unroll
      for (int nq = 0; nq < 2; nq++) {
        f32x4 t = cmv[nk0];                       // mask folded into acc init
        t = MFMA_BF16(a00, qf[nq][0], t);
        t = MFMA_BF16(a01, qf[nq][1], t);
        st0[nq] = t;
        f32x4 u = cmv[nk1];
        u = MFMA_BF16(a10, qf[nq][0], u);
        u = MFMA_BF16(a11, qf[nq][1], u);
        st1[nq] = u;
      }
      u16x8 pb[2];
#pragma unroll
      for (int nq = 0; nq < 2; nq++) {
#pragma unroll
        for (int r = 0; r < 4; r++) {
          st0[nq][r] = EXP2F(st0[nq][r]);
          st1[nq][r] = EXP2F(st1[nq][r]);
        }
        u32x4 pk;
        pk[0] = pack_trunc(st0[nq][0], st0[nq][1]);
        pk[1] = pack_trunc(st0[nq][2], st0[nq][3]);
        pk[2] = pack_trunc(st1[nq][0], st1[nq][1]);
        pk[3] = pack_trunc(st1[nq][2], st1[nq][3]);
        pb[nq] = __builtin_bit_cast(u16x8, pk);
      }
      const int voff = ((ks * 4 + fq) ^ fr) * 8;
#pragma unroll
      for (int di = 0; di < 4; di++) {
        const u16x8 vf = *(const u16x8*)(Vs + (di * 16 + fr) * 128 + voff);
#pragma unroll
        for (int nq = 0; nq < 2; nq++)
          Oa[di][nq] = MFMA_BF16(vf, pb[nq], Oa[di][nq]);
      }
#pragma unroll
      for (int nq = 0; nq < 2; nq++)
        lacc[nq] = MFMA_BF16(ones_f, pb[nq], lacc[nq]);
    }
  }

#pragma unroll
  for (int nq = 0; nq < 2; nq++) {
    const int lv = __builtin_amdgcn_ds_bpermute(fr * 4, __builtin_bit_cast(int, lacc[nq][0]));
    const float inv = 1.0f / __builtin_bit_cast(float, lv);
    const int sg = qt * 128 + wid * 32 + nq * 16 + fr;
    ushort_t* crow = ctx + ((size_t)(b * S_ + sg)) * D_ + h * DEPTH_;
#pragma unroll
    for (int di = 0; di < 4; di++) {
      u16x4 o4;
#pragma unroll
      for (int r = 0; r < 4; r++) o4[r] = f2bf(Oa[di][nq][r] * inv);
      *(u16x4*)(crow + di * 16 + fq * 4) = o4;
    }
  }
}

// ---------------- launch ----------------

extern "C" void kernel_launch(void* const* d_in, const int* in_sizes, int n_in,
                              void* d_out, int out_size, void* d_ws, size_t ws_size,
                              hipStream_t stream) {
  const float* v  = (const float*)d_in[0];
  const float* k  = (const float*)d_in[1];
  const float* q  = (const float*)d_in[2];
  const int* mask = (const int*)d_in[3];
  const float* Wq = (const float*)d_in[4];
  const float* bq = (const float*)d_in[5];
  const float* Wk = (const float*)d_in[6];
  const float* bk = (const float*)d_in[7];
  const float* Wv = (const float*)d_in[8];
  const float* bv = (const float*)d_in[9];
  const float* Wo = (const float*)d_in[10];
  const float* bo = (const float*)d_in[11];
  float* out = (float*)d_out;

  char* ws = (char*)d_ws;
  ushort_t* qb  = (ushort_t*)(ws);
  ushort_t* kb  = (ushort_t*)(ws + (size_t)(16u << 20));
  ushort_t* vb  = (ushort_t*)(ws + (size_t)(32u << 20));
  ushort_t* Wqt = (ushort_t*)(ws + (size_t)(48u << 20));
  ushort_t* Wkt = (ushort_t*)(ws + (size_t)(50u << 20));
  ushort_t* Wvt = (ushort_t*)(ws + (size_t)(52u << 20));
  ushort_t* Wot = (ushort_t*)(ws + (size_t)(54u << 20));
  ushort_t* Qh  = (ushort_t*)(ws + (size_t)(56u << 20));
  ushort_t* Kh  = (ushort_t*)(ws + (size_t)(72u << 20));
  ushort_t* Vht = (ushort_t*)(ws + (size_t)(88u << 20));
  ushort_t* ctx = qb;  // qb dead after projections

  cvt_kernel<<<dim3(8192, 4), 256, 0, stream>>>(q, k, v, Wq, Wk, Wv, Wo,
                                                qb, kb, vb, Wqt, Wkt, Wvt, Wot);
  qkv_gemm_kernel<<<dim3(512, 1, 3), 256, 0, stream>>>(qb, kb, vb, Wqt, Wkt, Wvt,
                                                       bq, bk, bv, Qh, Kh, Vht);
  attn_kernel<<<dim3(1024), 256, 0, stream>>>(Qh, Kh, Vht, mask, ctx);
  out_gemm_kernel<<<dim3(512), 256, 0, stream>>>(ctx, Wot, bo, out);
}

// Round 5
// 311.188 us; speedup vs baseline: 1.2835x; 1.2835x over previous
//
#include <hip/hip_runtime.h>

// MultiHeadAttention B=4,S=2048,D=1024,H=16,depth=64.
// R5: R3 base (324us). Mask folded into QK^T C-init via DIRECT LDS f32x4 reads
// (zero register live-range -- R4's register-array version spilled 92MB).
// Merged cvt dispatch kept. GEMM launch_bounds back to 3 (R3-proven).

typedef unsigned short ushort_t;
typedef __bf16          b16x8 __attribute__((ext_vector_type(8)));
typedef unsigned short  u16x8 __attribute__((ext_vector_type(8)));
typedef unsigned short  u16x4 __attribute__((ext_vector_type(4)));
typedef unsigned int    u32x4 __attribute__((ext_vector_type(4)));
typedef float           f32x4 __attribute__((ext_vector_type(4)));

#define B_ 4
#define S_ 2048
#define D_ 1024
#define H_ 16
#define DEPTH_ 64
#define LOG2E 1.4426950408889634f
#define MASKC (-1.4426950408889634e9f)

__device__ __forceinline__ unsigned short f2bf(float f) {
  unsigned u = __builtin_bit_cast(unsigned, f);
  u += 0x7FFFu + ((u >> 16) & 1u);   // RTNE
  return (unsigned short)(u >> 16);
}

__device__ __forceinline__ unsigned pack_trunc(float lo, float hi) {
#if __has_builtin(__builtin_amdgcn_perm)
  return __builtin_amdgcn_perm(__builtin_bit_cast(unsigned, hi),
                               __builtin_bit_cast(unsigned, lo), 0x07060302u);
#else
  return (__builtin_bit_cast(unsigned, hi) & 0xFFFF0000u) |
         (__builtin_bit_cast(unsigned, lo) >> 16);
#endif
}

#if __has_builtin(__builtin_amdgcn_exp2f)
#define EXP2F(x) __builtin_amdgcn_exp2f(x)
#else
#define EXP2F(x) exp2f(x)
#endif

#define GLD16(gp, lp) __builtin_amdgcn_global_load_lds( \
    (__attribute__((address_space(1))) void*)(gp),       \
    (__attribute__((address_space(3))) void*)(lp), 16, 0, 0)

#define MFMA_BF16(a, b, c) __builtin_amdgcn_mfma_f32_16x16x32_bf16( \
    __builtin_bit_cast(b16x8, (a)), __builtin_bit_cast(b16x8, (b)), (c), 0, 0, 0)

// ---------------- merged convert kernel ----------------

__global__ void cvt_kernel(const float* __restrict__ q, const float* __restrict__ k,
                           const float* __restrict__ v,
                           const float* __restrict__ Wq, const float* __restrict__ Wk,
                           const float* __restrict__ Wv, const float* __restrict__ Wo,
                           ushort_t* __restrict__ qb, ushort_t* __restrict__ kb,
                           ushort_t* __restrict__ vb,
                           ushort_t* __restrict__ Wqt, ushort_t* __restrict__ Wkt,
                           ushort_t* __restrict__ Wvt, ushort_t* __restrict__ Wot) {
  __shared__ float t[32][33];
  const int y = blockIdx.y;
  if (y < 3) {
    const float* src = y == 0 ? q : y == 1 ? k : v;
    ushort_t*    dst = y == 0 ? qb : y == 1 ? kb : vb;
    size_t i = ((size_t)blockIdx.x * 256 + threadIdx.x) * 4;
    float4 f = *(const float4*)(src + i);
    u16x4 o;
    o[0] = f2bf(f.x); o[1] = f2bf(f.y); o[2] = f2bf(f.z); o[3] = f2bf(f.w);
    *(u16x4*)(dst + i) = o;
    return;
  }
  const int x = blockIdx.x;
  if (x >= 4096) return;
  const int z = x >> 10, tile = x & 1023;
  const float* W = z == 0 ? Wq : z == 1 ? Wk : z == 2 ? Wv : Wo;
  ushort_t*   Wt = z == 0 ? Wqt : z == 1 ? Wkt : z == 2 ? Wvt : Wot;
  const int xx = threadIdx.x & 31, y0 = threadIdx.x >> 5;
  const int kt = (tile & 31) * 32, nt = (tile >> 5) * 32;
#pragma unroll
  for (int r = 0; r < 4; r++) {
    int row = y0 + r * 8;
    t[row][xx] = W[(size_t)(kt + row) * D_ + nt + xx];
  }
  __syncthreads();
#pragma unroll
  for (int r = 0; r < 4; r++) {
    int row = y0 + r * 8;
    Wt[(size_t)(nt + row) * D_ + kt + xx] = f2bf(t[xx][row]);
  }
}

// ---------------- GEMM core: 128x128 tile, BK=64, XOR-swizzled LDS ----------------

__device__ __forceinline__ void gemm_core(const ushort_t* __restrict__ A,
                                          const ushort_t* __restrict__ Bt,
                                          ushort_t* As, ushort_t* Bs,
                                          int tm, int tn, f32x4* acc) {
  const int tid = threadIdx.x;
  const int lane = tid & 63, wid = tid >> 6;
  const int wm = (wid >> 1) * 64, wn = (wid & 1) * 64;
  const int srow = lane >> 3;
  const int scol = ((lane & 7) ^ srow) * 8;
  const ushort_t* gA[4];
  const ushort_t* gB[4];
#pragma unroll
  for (int c = 0; c < 4; c++) {
    const int ch = wid * 4 + c;
    gA[c] = A  + (size_t)(tm + ch * 8 + srow) * D_ + scol;
    gB[c] = Bt + (size_t)(tn + ch * 8 + srow) * D_ + scol;
  }
  const int fr = lane & 15, fq = lane >> 4;
#pragma unroll
  for (int i = 0; i < 16; i++) acc[i] = f32x4{0.f, 0.f, 0.f, 0.f};
  for (int k0 = 0; k0 < D_; k0 += 64) {
    __syncthreads();
#pragma unroll
    for (int c = 0; c < 4; c++) {
      const int ch = wid * 4 + c;
      GLD16(gA[c] + k0, As + ch * 512);
      GLD16(gB[c] + k0, Bs + ch * 512);
    }
    __syncthreads();
#pragma unroll
    for (int kh = 0; kh < 2; kh++) {
      const int coff = (((kh * 4 + fq) ^ (fr & 7))) * 8;
      u16x8 af[4], bf[4];
#pragma unroll
      for (int mi = 0; mi < 4; mi++)
        af[mi] = *(const u16x8*)(As + (wm + mi * 16 + fr) * 64 + coff);
#pragma unroll
      for (int ni = 0; ni < 4; ni++)
        bf[ni] = *(const u16x8*)(Bs + (wn + ni * 16 + fr) * 64 + coff);
#pragma unroll
      for (int mi = 0; mi < 4; mi++)
#pragma unroll
        for (int ni = 0; ni < 4; ni++)
          acc[mi * 4 + ni] = MFMA_BF16(af[mi], bf[ni], acc[mi * 4 + ni]);
    }
  }
}

__device__ __forceinline__ int sigma32(int k5) {
  return ((k5 & 15) >> 2) * 8 + ((k5 >> 4) & 1) * 4 + (k5 & 3);
}

__device__ __forceinline__ void gemm_tile_swizzle(int bx, int& tm, int& tn) {
  const int xcd = bx & 7, j = bx >> 3;
  tn = (j & 7) * 128;
  tm = (((j >> 3) << 3) | xcd) * 128;
}

// z=0: Q*log2e/8 -> Qh [B,H,S,64]; z=1: K -> Kh; z=2: V -> Vht [B,H,64,S~sigma]
__global__ __launch_bounds__(256, 3) void qkv_gemm_kernel(
    const ushort_t* __restrict__ qb, const ushort_t* __restrict__ kb, const ushort_t* __restrict__ vb,
    const ushort_t* __restrict__ Wqt, const ushort_t* __restrict__ Wkt, const ushort_t* __restrict__ Wvt,
    const float* __restrict__ bq, const float* __restrict__ bk, const float* __restrict__ bv,
    ushort_t* __restrict__ Qh, ushort_t* __restrict__ Kh, ushort_t* __restrict__ Vht) {
  __shared__ __align__(16) ushort_t smem[128 * 136];
  ushort_t* As = smem;
  ushort_t* Bs = smem + 8192;
  const int z = blockIdx.z;
  const ushort_t* A  = z == 0 ? qb : z == 1 ? kb : vb;
  const ushort_t* Bt = z == 0 ? Wqt : z == 1 ? Wkt : Wvt;
  const float* bias  = z == 0 ? bq : z == 1 ? bk : bv;
  int tm, tn;
  gemm_tile_swizzle(blockIdx.x, tm, tn);
  f32x4 acc[16];
  gemm_core(A, Bt, As, Bs, tm, tn, acc);
  const int lane = threadIdx.x & 63, wid = threadIdx.x >> 6;
  const int wm = (wid >> 1) * 64, wn = (wid & 1) * 64;
  const int fr = lane & 15, rq = (lane >> 4) * 4;
  if (z == 2) {
    __syncthreads();
    ushort_t* trans = smem;
#pragma unroll
    for (int ni = 0; ni < 4; ni++) {
      const int n = wn + ni * 16 + fr;
      const float bb = bias[tn + n];
#pragma unroll
      for (int mi = 0; mi < 4; mi++) {
#pragma unroll
        for (int r = 0; r < 4; r++) {
          const int m = wm + mi * 16 + rq + r;
          const int mp = (m & ~31) + sigma32(m & 31);
          trans[n * 136 + mp] = f2bf(acc[mi * 4 + ni][r] + bb);
        }
      }
    }
    __syncthreads();
    const int n = threadIdx.x >> 1, hf = threadIdx.x & 1;
    const int col = tn + n, hh = col >> 6, dd = col & 63;
    const int bI = tm >> 11, sb = (tm & 2047) + hf * 64;
    ushort_t* dst = Vht + ((size_t)(bI * H_ + hh) * DEPTH_ + dd) * S_ + sb;
    const ushort_t* srcp = trans + n * 136 + hf * 64;
#pragma unroll
    for (int i = 0; i < 8; i++)
      *(u16x8*)(dst + i * 8) = *(const u16x8*)(srcp + i * 8);
  } else {
    ushort_t* outp = (z == 0) ? Qh : Kh;
    const float qscale = (z == 0) ? 0.125f * LOG2E : 1.0f;
#pragma unroll
    for (int ni = 0; ni < 4; ni++) {
      const int col = tn + wn + ni * 16 + fr;
      const float bb = bias[col];
      const int h = col >> 6, dd = col & 63;
#pragma unroll
      for (int mi = 0; mi < 4; mi++) {
#pragma unroll
        for (int r = 0; r < 4; r++) {
          const int m = tm + wm + mi * 16 + rq + r;
          const int b = m >> 11, s = m & 2047;
          outp[((size_t)(b * H_ + h) * S_ + s) * DEPTH_ + dd] =
              f2bf((acc[mi * 4 + ni][r] + bb) * qscale);
        }
      }
    }
  }
}

__global__ __launch_bounds__(256, 3) void out_gemm_kernel(
    const ushort_t* __restrict__ ctx, const ushort_t* __restrict__ Wot,
    const float* __restrict__ bo, float* __restrict__ out) {
  __shared__ __align__(16) ushort_t As[8192], Bs[8192];
  int tm, tn;
  gemm_tile_swizzle(blockIdx.x, tm, tn);
  f32x4 acc[16];
  gemm_core(ctx, Wot, As, Bs, tm, tn, acc);
  const int lane = threadIdx.x & 63, wid = threadIdx.x >> 6;
  const int wm = (wid >> 1) * 64, wn = (wid & 1) * 64;
  const int fr = lane & 15, rq = (lane >> 4) * 4;
#pragma unroll
  for (int ni = 0; ni < 4; ni++) {
    const int col = tn + wn + ni * 16 + fr;
    const float bb = bo[col];
#pragma unroll
    for (int mi = 0; mi < 4; mi++) {
#pragma unroll
      for (int r = 0; r < 4; r++) {
        const int m = tm + wm + mi * 16 + rq + r;
        out[(size_t)m * D_ + col] = acc[mi * 4 + ni][r] + bb;
      }
    }
  }
}

// ---------------- flash attention, S^T orientation ----------------
// Mask lives in LDS (Cm, log2-domain additive) and is consumed DIRECTLY as the
// QK^T MFMA C-init (f32x4 ds_read -> MFMA C operand, no register arrays).

__global__ __launch_bounds__(256, 4) void attn_kernel(
    const ushort_t* __restrict__ Qh, const ushort_t* __restrict__ Kh,
    const ushort_t* __restrict__ Vht, const int* __restrict__ mask,
    ushort_t* __restrict__ ctx) {
  __shared__ __align__(16) ushort_t Ks[128 * 64];   // [key][d], chunks ^ (row&7)
  __shared__ __align__(16) ushort_t Vs[64 * 128];   // [d][key-sigma], chunks ^ (row&15)
  __shared__ __align__(16) float Cm[2048];          // additive mask, log2 domain
  const int tid = threadIdx.x, lane = tid & 63, wid = tid >> 6;
  const int id = blockIdx.x;
  const int xcd = id & 7, j = id >> 3;
  const int qt = j & 15;
  const int bh = xcd * 8 + (j >> 4);
  const int b = bh >> 4, h = bh & 15;
  const size_t base = (size_t)bh * (S_ * DEPTH_);
  const int fr = lane & 15, fq = lane >> 4;

  const int* mrow = mask + b * S_;
#pragma unroll
  for (int i = 0; i < 8; i++) {
    const int idx = tid + i * 256;
    Cm[idx] = mrow[idx] ? MASKC : 0.0f;
  }

  u16x8 qf[2][2];
#pragma unroll
  for (int nq = 0; nq < 2; nq++)
#pragma unroll
    for (int kc = 0; kc < 2; kc++)
      qf[nq][kc] = *(const u16x8*)(Qh + base +
          (size_t)(qt * 128 + wid * 32 + nq * 16 + fr) * DEPTH_ + kc * 32 + fq * 8);

  u16x8 ones_f;
  {
    const unsigned short o = (fr == 0) ? (unsigned short)0x3F80 : (unsigned short)0;
#pragma unroll
    for (int jj = 0; jj < 8; jj++) ones_f[jj] = o;
  }

  f32x4 Oa[4][2];
  f32x4 lacc[2];
#pragma unroll
  for (int di = 0; di < 4; di++)
#pragma unroll
    for (int nq = 0; nq < 2; nq++) Oa[di][nq] = f32x4{0.f, 0.f, 0.f, 0.f};
#pragma unroll
  for (int nq = 0; nq < 2; nq++) lacc[nq] = f32x4{0.f, 0.f, 0.f, 0.f};

  const int krow = lane >> 3;
  const int kcolL = ((lane & 7) ^ (krow & 7)) * 8;
  const int vrowc = lane >> 4;
  const int koff0 = ((0 + fq) ^ (fr & 7)) * 8;
  const int koff1 = ((4 + fq) ^ (fr & 7)) * 8;

  for (int kt = 0; kt < 16; kt++) {
    __syncthreads();
#pragma unroll
    for (int c = 0; c < 4; c++) {
      const int ch = wid * 4 + c;
      GLD16(Kh + base + (size_t)(kt * 128 + ch * 8 + krow) * DEPTH_ + kcolL, Ks + ch * 512);
      const int vrow = ch * 4 + vrowc;
      const int vcolL = ((lane & 15) ^ (vrow & 15)) * 8;
      GLD16(Vht + base + (size_t)vrow * S_ + kt * 128 + vcolL, Vs + ch * 512);
    }
    __syncthreads();

#pragma unroll
    for (int ks = 0; ks < 4; ks++) {
      const int nk0 = ks * 2, nk1 = nk0 + 1;
      const ushort_t* kr0 = Ks + (nk0 * 16 + fr) * 64;
      const ushort_t* kr1 = Ks + (nk1 * 16 + fr) * 64;
      const u16x8 a00 = *(const u16x8*)(kr0 + koff0);
      const u16x8 a01 = *(const u16x8*)(kr0 + koff1);
      const u16x8 a10 = *(const u16x8*)(kr1 + koff0);
      const u16x8 a11 = *(const u16x8*)(kr1 + koff1);
      f32x4 st0[2], st1[2];
#pragma unroll
      for (int nq = 0; nq < 2; nq++) {
        // mask folded into accumulator init, read straight from LDS
        f32x4 t = *(const f32x4*)(Cm + kt * 128 + nk0 * 16 + fq * 4);
        t = MFMA_BF16(a00, qf[nq][0], t);
        t = MFMA_BF16(a01, qf[nq][1], t);
        st0[nq] = t;
        f32x4 u = *(const f32x4*)(Cm + kt * 128 + nk1 * 16 + fq * 4);
        u = MFMA_BF16(a10, qf[nq][0], u);
        u = MFMA_BF16(a11, qf[nq][1], u);
        st1[nq] = u;
      }
      u16x8 pb[2];
#pragma unroll
      for (int nq = 0; nq < 2; nq++) {
#pragma unroll
        for (int r = 0; r < 4; r++) {
          st0[nq][r] = EXP2F(st0[nq][r]);
          st1[nq][r] = EXP2F(st1[nq][r]);
        }
        u32x4 pk;
        pk[0] = pack_trunc(st0[nq][0], st0[nq][1]);
        pk[1] = pack_trunc(st0[nq][2], st0[nq][3]);
        pk[2] = pack_trunc(st1[nq][0], st1[nq][1]);
        pk[3] = pack_trunc(st1[nq][2], st1[nq][3]);
        pb[nq] = __builtin_bit_cast(u16x8, pk);
      }
      const int voff = ((ks * 4 + fq) ^ fr) * 8;
#pragma unroll
      for (int di = 0; di < 4; di++) {
        const u16x8 vf = *(const u16x8*)(Vs + (di * 16 + fr) * 128 + voff);
#pragma unroll
        for (int nq = 0; nq < 2; nq++)
          Oa[di][nq] = MFMA_BF16(vf, pb[nq], Oa[di][nq]);
      }
#pragma unroll
      for (int nq = 0; nq < 2; nq++)
        lacc[nq] = MFMA_BF16(ones_f, pb[nq], lacc[nq]);
    }
  }

#pragma unroll
  for (int nq = 0; nq < 2; nq++) {
    const int lv = __builtin_amdgcn_ds_bpermute(fr * 4, __builtin_bit_cast(int, lacc[nq][0]));
    const float inv = 1.0f / __builtin_bit_cast(float, lv);
    const int sg = qt * 128 + wid * 32 + nq * 16 + fr;
    ushort_t* crow = ctx + ((size_t)(b * S_ + sg)) * D_ + h * DEPTH_;
#pragma unroll
    for (int di = 0; di < 4; di++) {
      u16x4 o4;
#pragma unroll
      for (int r = 0; r < 4; r++) o4[r] = f2bf(Oa[di][nq][r] * inv);
      *(u16x4*)(crow + di * 16 + fq * 4) = o4;
    }
  }
}

// ---------------- launch ----------------

extern "C" void kernel_launch(void* const* d_in, const int* in_sizes, int n_in,
                              void* d_out, int out_size, void* d_ws, size_t ws_size,
                              hipStream_t stream) {
  const float* v  = (const float*)d_in[0];
  const float* k  = (const float*)d_in[1];
  const float* q  = (const float*)d_in[2];
  const int* mask = (const int*)d_in[3];
  const float* Wq = (const float*)d_in[4];
  const float* bq = (const float*)d_in[5];
  const float* Wk = (const float*)d_in[6];
  const float* bk = (const float*)d_in[7];
  const float* Wv = (const float*)d_in[8];
  const float* bv = (const float*)d_in[9];
  const float* Wo = (const float*)d_in[10];
  const float* bo = (const float*)d_in[11];
  float* out = (float*)d_out;

  char* ws = (char*)d_ws;
  ushort_t* qb  = (ushort_t*)(ws);
  ushort_t* kb  = (ushort_t*)(ws + (size_t)(16u << 20));
  ushort_t* vb  = (ushort_t*)(ws + (size_t)(32u << 20));
  ushort_t* Wqt = (ushort_t*)(ws + (size_t)(48u << 20));
  ushort_t* Wkt = (ushort_t*)(ws + (size_t)(50u << 20));
  ushort_t* Wvt = (ushort_t*)(ws + (size_t)(52u << 20));
  ushort_t* Wot = (ushort_t*)(ws + (size_t)(54u << 20));
  ushort_t* Qh  = (ushort_t*)(ws + (size_t)(56u << 20));
  ushort_t* Kh  = (ushort_t*)(ws + (size_t)(72u << 20));
  ushort_t* Vht = (ushort_t*)(ws + (size_t)(88u << 20));
  ushort_t* ctx = qb;  // qb dead after projections

  cvt_kernel<<<dim3(8192, 4), 256, 0, stream>>>(q, k, v, Wq, Wk, Wv, Wo,
                                                qb, kb, vb, Wqt, Wkt, Wvt, Wot);
  qkv_gemm_kernel<<<dim3(512, 1, 3), 256, 0, stream>>>(qb, kb, vb, Wqt, Wkt, Wvt,
                                                       bq, bk, bv, Qh, Kh, Vht);
  attn_kernel<<<dim3(1024), 256, 0, stream>>>(Qh, Kh, Vht, mask, ctx);
  out_gemm_kernel<<<dim3(512), 256, 0, stream>>>(ctx, Wot, bo, out);
}